// Round 6
// baseline (1463.464 us; speedup 1.0000x reference)
//
#include <hip/hip_runtime.h>
#include <math.h>

#define B_ 8
#define C_ 256
#define H_ 128
#define W_ 128
#define HW_ (H_*W_)                 // 16384
#define PLANE ((size_t)C_*HW_)      // 4194304 elems per batch image

typedef __attribute__((ext_vector_type(8))) short short8;   // 8 bf16 (4 VGPR)
typedef __attribute__((ext_vector_type(4))) float f32x4;    // MFMA acc

// f32 -> bf16 (round-to-nearest-even), bit pattern in ushort
static __device__ __forceinline__ unsigned short f2bf(float f) {
    unsigned u = __float_as_uint(f);
    u += 0x7FFF + ((u >> 16) & 1);
    return (unsigned short)(u >> 16);
}
static __device__ __forceinline__ float bf2f(unsigned short h) {
    return __uint_as_float(((unsigned)h) << 16);
}

// Swizzle for [rows][32]-bf16 planes (row stride 64B): XOR bits 4..6 by row&7.
// Bijective, preserves bits 0..3 (16B-chunk alignment kept).
#define SWZ(row, kbyte) ((((row) << 6) | (kbyte)) ^ (((row) & 7) << 4))
// Swizzle for [rows][256]-bf16 panel planes (row stride 512B): same XOR trick.
#define PSWZ(row, kbyte) ((((row) << 9) | (kbyte)) ^ (((row) & 7) << 4))

// ---------------------------------------------------------------------------
// conv1x1 via MFMA bf16x3, PANEL structure:
// Block = (batch b, one 128-pixel strip). Stage X panel [128 p][256 ci] once
// (hi/lo bf16, swizzled, 128KB LDS), then loop all 8 co-blocks x 8 k-steps
// barrier-free: A (weights) read from global f32 + inline hi/lo split (L2-hot),
// B fragments ds_read_b128 from the panel. acc[s][cr][pr], D col=p, row=co.
// 1 block/CU by LDS (intentional).
// ---------------------------------------------------------------------------
template<int NS, bool RESID>
__global__ __launch_bounds__(256)
void conv_panel(const float* __restrict__ X,
                const float* __restrict__ W0, const float* __restrict__ W1,
                const float* __restrict__ W2,
                const float* __restrict__ Bi0, const float* __restrict__ Bi1,
                const float* __restrict__ Bi2,
                const float* __restrict__ resid,
                float* __restrict__ Y0, float* __restrict__ Y1,
                float* __restrict__ Y2)
{
    __shared__ unsigned short PH[32768], PL[32768];   // 64KB + 64KB panel
    __shared__ float biasL[NS * 256];

    const int b    = blockIdx.z;
    const int p0   = blockIdx.x << 7;
    const int t    = threadIdx.x;
    const int lane = t & 63;
    const int wv   = t >> 6;
    const int l15  = lane & 15;
    const int l4   = lane >> 4;

    const float* Wp[3] = {W0, W1, W2};
    const float* Bp[3] = {Bi0, Bi1, Bi2};
    float*       Yp[3] = {Y0, Y1, Y2};
    const float* Xb = X + (size_t)b * PLANE;

#pragma unroll
    for (int s = 0; s < NS; ++s) biasL[s * 256 + t] = Bp[s][t];

    // ---- stage panel: read coalesced along p, transpose-split into LDS ----
#pragma unroll
    for (int i = 0; i < 32; ++i) {
        const int idx = t + (i << 8);        // 0..8191 float4s
        const int ci  = idx >> 5;            // 0..255
        const int p4  = (idx & 31) << 2;     // 0..124
        const float4 x4 = *(const float4*)(Xb + (size_t)ci * HW_ + (p0 + p4));
        const float xe[4] = {x4.x, x4.y, x4.z, x4.w};
#pragma unroll
        for (int e = 0; e < 4; ++e) {
            const unsigned short hh = f2bf(xe[e]);
            const unsigned short ll = f2bf(xe[e] - bf2f(hh));
            const int off = PSWZ(p4 + e, ci << 1);
            *(unsigned short*)((char*)PH + off) = hh;
            *(unsigned short*)((char*)PL + off) = ll;
        }
    }
    __syncthreads();

    const size_t ybase = (size_t)b * PLANE;
    const int pcol = p0 + (wv << 5) + l15;

    for (int coblk = 0; coblk < 8; ++coblk) {
        f32x4 acc[NS][2][2];
#pragma unroll
        for (int s = 0; s < NS; ++s)
#pragma unroll
            for (int cr = 0; cr < 2; ++cr)
#pragma unroll
                for (int pr = 0; pr < 2; ++pr)
                    acc[s][cr][pr] = (f32x4){0.f, 0.f, 0.f, 0.f};

#pragma unroll 2
        for (int ks = 0; ks < 8; ++ks) {
            const int k0 = ks << 5;
            // B fragments from panel (shared across all s, cr)
            short8 bh[2], bl[2];
#pragma unroll
            for (int pr = 0; pr < 2; ++pr) {
                const int prow = (wv << 5) + (pr << 4) + l15;
                const int off  = PSWZ(prow, (k0 + (l4 << 3)) << 1);
                bh[pr] = *(short8*)((char*)PH + off);
                bl[pr] = *(short8*)((char*)PL + off);
            }
            // A fragments straight from global W (L2-hot) + inline hi/lo split
#pragma unroll
            for (int s = 0; s < NS; ++s) {
#pragma unroll
                for (int cr = 0; cr < 2; ++cr) {
                    const int co = (coblk << 5) + (cr << 4) + l15;
                    const float* wr = Wp[s] + (size_t)co * C_ + (k0 + (l4 << 3));
                    const float4 wa = *(const float4*)wr;
                    const float4 wb = *(const float4*)(wr + 4);
                    const float wf[8] = {wa.x, wa.y, wa.z, wa.w,
                                         wb.x, wb.y, wb.z, wb.w};
                    short8 ah, al;
#pragma unroll
                    for (int j = 0; j < 8; ++j) {
                        const unsigned short h = f2bf(wf[j]);
                        ah[j] = (short)h;
                        al[j] = (short)f2bf(wf[j] - bf2f(h));
                    }
#pragma unroll
                    for (int pr = 0; pr < 2; ++pr) {
                        acc[s][cr][pr] = __builtin_amdgcn_mfma_f32_16x16x32_bf16(
                            ah, bh[pr], acc[s][cr][pr], 0, 0, 0);
                        acc[s][cr][pr] = __builtin_amdgcn_mfma_f32_16x16x32_bf16(
                            ah, bl[pr], acc[s][cr][pr], 0, 0, 0);
                        acc[s][cr][pr] = __builtin_amdgcn_mfma_f32_16x16x32_bf16(
                            al, bh[pr], acc[s][cr][pr], 0, 0, 0);
                    }
                }
            }
        }

        // ---- epilogue for this co-block (spreads writes through block) ----
#pragma unroll
        for (int s = 0; s < NS; ++s) {
#pragma unroll
            for (int cr = 0; cr < 2; ++cr) {
#pragma unroll
                for (int pr = 0; pr < 2; ++pr) {
                    const f32x4 a = acc[s][cr][pr];
#pragma unroll
                    for (int r = 0; r < 4; ++r) {
                        const int co = (coblk << 5) + (cr << 4) + (l4 << 2) + r;
                        const size_t addr = ybase + (size_t)co * HW_
                                          + (size_t)(pcol + (pr << 4));
                        float val = a[r] + biasL[s * 256 + co];
                        if (RESID) val += resid[addr];
                        Yp[s][addr] = val;
                    }
                }
            }
        }
    }
}

// ---------------------------------------------------------------------------
// scores via MFMA bf16x3 (UNCHANGED from round 5):
// per (b,c): ST[v][w] = sum_h Q[h][v]*K[h][w], in place over Q slice.
// ---------------------------------------------------------------------------
__global__ __launch_bounds__(256)
void scores_mfma(const float* __restrict__ Kt, float* __restrict__ Q)
{
    __shared__ unsigned short QTh[128 * 32], QTl[128 * 32];
    __shared__ unsigned short KTh[128 * 32], KTl[128 * 32];

    const int bc = blockIdx.x;
    const float* Kp = Kt + (size_t)bc * HW_;
    const float* Qp = Q  + (size_t)bc * HW_;
    const int t = threadIdx.x, lane = t & 63, wv = t >> 6;

    const int hhp = t & 15;
    const int vc  = (t >> 4) << 3;
    const int kb  = (lane >> 4) << 4;

    f32x4 acc[2][8];
#pragma unroll
    for (int mr = 0; mr < 2; ++mr)
#pragma unroll
        for (int nr = 0; nr < 8; ++nr)
            acc[mr][nr] = (f32x4){0.f, 0.f, 0.f, 0.f};

    for (int h0 = 0; h0 < H_; h0 += 32) {
        float qv[2][8], kv[2][8];
#pragma unroll
        for (int j = 0; j < 2; ++j) {
            const int hh = h0 + (hhp << 1) + j;
            const float4 q0 = *(const float4*)(Qp + (size_t)hh * W_ + vc);
            const float4 q1 = *(const float4*)(Qp + (size_t)hh * W_ + vc + 4);
            const float4 k0 = *(const float4*)(Kp + (size_t)hh * W_ + vc);
            const float4 k1 = *(const float4*)(Kp + (size_t)hh * W_ + vc + 4);
            qv[j][0]=q0.x; qv[j][1]=q0.y; qv[j][2]=q0.z; qv[j][3]=q0.w;
            qv[j][4]=q1.x; qv[j][5]=q1.y; qv[j][6]=q1.z; qv[j][7]=q1.w;
            kv[j][0]=k0.x; kv[j][1]=k0.y; kv[j][2]=k0.z; kv[j][3]=k0.w;
            kv[j][4]=k1.x; kv[j][5]=k1.y; kv[j][6]=k1.z; kv[j][7]=k1.w;
        }
#pragma unroll
        for (int e = 0; e < 8; ++e) {
            const int v = vc + e;
            const int off = SWZ(v, hhp << 2);
            const unsigned short qh0 = f2bf(qv[0][e]), qh1 = f2bf(qv[1][e]);
            const unsigned short kh0 = f2bf(kv[0][e]), kh1 = f2bf(kv[1][e]);
            *(ushort2*)((char*)QTh + off) = (ushort2){qh0, qh1};
            *(ushort2*)((char*)QTl + off) = (ushort2){f2bf(qv[0][e] - bf2f(qh0)),
                                                      f2bf(qv[1][e] - bf2f(qh1))};
            *(ushort2*)((char*)KTh + off) = (ushort2){kh0, kh1};
            *(ushort2*)((char*)KTl + off) = (ushort2){f2bf(kv[0][e] - bf2f(kh0)),
                                                      f2bf(kv[1][e] - bf2f(kh1))};
        }
        __syncthreads();

        short8 bh[8], bl[8];
#pragma unroll
        for (int nr = 0; nr < 8; ++nr) {
            const int wrow = (nr << 4) + (lane & 15);
            bh[nr] = *(short8*)((char*)KTh + SWZ(wrow, kb));
            bl[nr] = *(short8*)((char*)KTl + SWZ(wrow, kb));
        }
#pragma unroll
        for (int mr = 0; mr < 2; ++mr) {
            const int vrow = (wv << 5) + (mr << 4) + (lane & 15);
            const short8 ah = *(short8*)((char*)QTh + SWZ(vrow, kb));
            const short8 al = *(short8*)((char*)QTl + SWZ(vrow, kb));
#pragma unroll
            for (int nr = 0; nr < 8; ++nr) {
                acc[mr][nr] = __builtin_amdgcn_mfma_f32_16x16x32_bf16(ah, bh[nr], acc[mr][nr], 0, 0, 0);
                acc[mr][nr] = __builtin_amdgcn_mfma_f32_16x16x32_bf16(ah, bl[nr], acc[mr][nr], 0, 0, 0);
                acc[mr][nr] = __builtin_amdgcn_mfma_f32_16x16x32_bf16(al, bh[nr], acc[mr][nr], 0, 0, 0);
            }
        }
        __syncthreads();
    }

    float* Sp = Q + (size_t)bc * HW_;
    const int r4 = (lane >> 4) << 2;
#pragma unroll
    for (int mr = 0; mr < 2; ++mr) {
#pragma unroll
        for (int nr = 0; nr < 8; ++nr) {
            const f32x4 a = acc[mr][nr];
            const int w = (nr << 4) + (lane & 15);
#pragma unroll
            for (int r = 0; r < 4; ++r) {
                const int v = (wv << 5) + (mr << 4) + r4 + r;
                Sp[(size_t)v * W_ + w] = a[r];
            }
        }
    }
}

// ---------------------------------------------------------------------------
// softmax over batch axis; emits attn^T bf16 hi/lo pre-swizzled tiles.
// (UNCHANGED from round 5)
// ---------------------------------------------------------------------------
__global__ __launch_bounds__(256)
void softmax_pack(const float* __restrict__ S,
                  unsigned short* __restrict__ aH, unsigned short* __restrict__ aL)
{
    const size_t N = (size_t)C_ * HW_;
    const size_t idx = ((size_t)blockIdx.x * 256 + threadIdx.x) << 2;
    if (idx >= N) return;

    float4 vals[B_];
#pragma unroll
    for (int b = 0; b < B_; ++b) vals[b] = *(const float4*)(S + (size_t)b * N + idx);

    float4 mx = vals[0];
#pragma unroll
    for (int b = 1; b < B_; ++b) {
        mx.x = fmaxf(mx.x, vals[b].x); mx.y = fmaxf(mx.y, vals[b].y);
        mx.z = fmaxf(mx.z, vals[b].z); mx.w = fmaxf(mx.w, vals[b].w);
    }
    float4 sum = {0.f, 0.f, 0.f, 0.f};
#pragma unroll
    for (int b = 0; b < B_; ++b) {
        vals[b].x = expf(vals[b].x - mx.x); sum.x += vals[b].x;
        vals[b].y = expf(vals[b].y - mx.y); sum.y += vals[b].y;
        vals[b].z = expf(vals[b].z - mx.z); sum.z += vals[b].z;
        vals[b].w = expf(vals[b].w - mx.w); sum.w += vals[b].w;
    }
    const float4 inv = {1.f / sum.x, 1.f / sum.y, 1.f / sum.z, 1.f / sum.w};

    const int c = (int)(idx >> 14);
    const int r = (int)(idx & 16383);
    const int v = r >> 7, w = r & 127;
    const size_t tile_byte = ((size_t)(c << 2) + (w >> 5)) * 8192 + SWZ(v, (w & 31) << 1);

#pragma unroll
    for (int b = 0; b < B_; ++b) {
        const float o0 = vals[b].x * inv.x, o1 = vals[b].y * inv.y,
                    o2 = vals[b].z * inv.z, o3 = vals[b].w * inv.w;
        const unsigned short h0 = f2bf(o0), h1 = f2bf(o1),
                             h2 = f2bf(o2), h3 = f2bf(o3);
        char* bh = (char*)(aH + (size_t)b * N) + tile_byte;
        char* bl = (char*)(aL + (size_t)b * N) + tile_byte;
        *(ushort4*)bh = (ushort4){h0, h1, h2, h3};
        *(ushort4*)bl = (ushort4){f2bf(o0 - bf2f(h0)), f2bf(o1 - bf2f(h1)),
                                  f2bf(o2 - bf2f(h2)), f2bf(o3 - bf2f(h3))};
    }
}

// ---------------------------------------------------------------------------
// AV via MFMA bf16x3 (UNCHANGED from round 5):
// per (b,c): O[h][v] = sum_w V[h][w]*attnT[v][w], in place over V slice.
// ---------------------------------------------------------------------------
__global__ __launch_bounds__(256)
void av_mfma(float* __restrict__ V,
             const unsigned short* __restrict__ aH,
             const unsigned short* __restrict__ aL)
{
    __shared__ unsigned short Vh[128 * 32], Vl[128 * 32];
    __shared__ unsigned short Ath[128 * 32], Atl[128 * 32];

    const int bc = blockIdx.x;
    float* Vp = V + (size_t)bc * HW_;
    const int t = threadIdx.x, lane = t & 63, wv = t >> 6;
    const int kb = (lane >> 4) << 4;

    const int hrow = t >> 1;
    const int wc   = (t & 1) << 4;

    f32x4 acc[2][8];
#pragma unroll
    for (int mr = 0; mr < 2; ++mr)
#pragma unroll
        for (int nr = 0; nr < 8; ++nr)
            acc[mr][nr] = (f32x4){0.f, 0.f, 0.f, 0.f};

    for (int ks = 0; ks < 4; ++ks) {
        const int w0 = ks << 5;
#pragma unroll
        for (int f = 0; f < 4; ++f) {
            const int wl = wc + (f << 2);
            const float4 v4 = *(const float4*)(Vp + (size_t)hrow * W_ + w0 + wl);
            const unsigned short h0 = f2bf(v4.x), h1 = f2bf(v4.y),
                                 h2 = f2bf(v4.z), h3 = f2bf(v4.w);
            const int off = SWZ(hrow, wl << 1);
            *(ushort4*)((char*)Vh + off) = (ushort4){h0, h1, h2, h3};
            *(ushort4*)((char*)Vl + off) = (ushort4){f2bf(v4.x - bf2f(h0)), f2bf(v4.y - bf2f(h1)),
                                                     f2bf(v4.z - bf2f(h2)), f2bf(v4.w - bf2f(h3))};
        }
        {
            const size_t tb = ((size_t)(bc << 2) + ks) << 12;
            const uint4* gh = (const uint4*)(aH + tb);
            const uint4* gl = (const uint4*)(aL + tb);
            ((uint4*)Ath)[t]       = gh[t];
            ((uint4*)Ath)[t + 256] = gh[t + 256];
            ((uint4*)Atl)[t]       = gl[t];
            ((uint4*)Atl)[t + 256] = gl[t + 256];
        }
        __syncthreads();

        short8 bh[8], bl[8];
#pragma unroll
        for (int nr = 0; nr < 8; ++nr) {
            const int vrow = (nr << 4) + (lane & 15);
            bh[nr] = *(short8*)((char*)Ath + SWZ(vrow, kb));
            bl[nr] = *(short8*)((char*)Atl + SWZ(vrow, kb));
        }
#pragma unroll
        for (int mr = 0; mr < 2; ++mr) {
            const int hr = (wv << 5) + (mr << 4) + (lane & 15);
            const short8 ah = *(short8*)((char*)Vh + SWZ(hr, kb));
            const short8 al = *(short8*)((char*)Vl + SWZ(hr, kb));
#pragma unroll
            for (int nr = 0; nr < 8; ++nr) {
                acc[mr][nr] = __builtin_amdgcn_mfma_f32_16x16x32_bf16(ah, bh[nr], acc[mr][nr], 0, 0, 0);
                acc[mr][nr] = __builtin_amdgcn_mfma_f32_16x16x32_bf16(ah, bl[nr], acc[mr][nr], 0, 0, 0);
                acc[mr][nr] = __builtin_amdgcn_mfma_f32_16x16x32_bf16(al, bh[nr], acc[mr][nr], 0, 0, 0);
            }
        }
        __syncthreads();
    }

    const int r4 = (lane >> 4) << 2;
#pragma unroll
    for (int mr = 0; mr < 2; ++mr) {
#pragma unroll
        for (int nr = 0; nr < 8; ++nr) {
            const f32x4 a = acc[mr][nr];
            const int vcol = (nr << 4) + (lane & 15);
#pragma unroll
            for (int r = 0; r < 4; ++r) {
                const int h = (wv << 5) + (mr << 4) + r4 + r;
                Vp[(size_t)h * W_ + vcol] = a[r];
            }
        }
    }
}

// ---------------------------------------------------------------------------
extern "C" void kernel_launch(void* const* d_in, const int* in_sizes, int n_in,
                              void* d_out, int out_size, void* d_ws, size_t ws_size,
                              hipStream_t stream)
{
    const float* x  = (const float*)d_in[0];
    const float* wk = (const float*)d_in[1];
    const float* bk = (const float*)d_in[2];
    const float* wq = (const float*)d_in[3];
    const float* bq = (const float*)d_in[4];
    const float* wv = (const float*)d_in[5];
    const float* bv = (const float*)d_in[6];
    const float* wo = (const float*)d_in[7];
    const float* bo = (const float*)d_in[8];
    float* out = (float*)d_out;

    const size_t NBUF = (size_t)B_ * PLANE;   // 33554432 elems
    float* kbuf = (float*)d_ws;               // k -> (dead) -> attn hi/lo packed
    float* qbuf = kbuf + NBUF;                // q -> ST (in place)
    float* vbuf = qbuf + NBUF;                // v -> out2 (in place)
    unsigned short* attnH = (unsigned short*)kbuf;
    unsigned short* attnL = attnH + NBUF;

    // fused k/q/v conv, panel structure
    const dim3 gP(HW_ / 128, 1, B_);
    conv_panel<3, false><<<gP, 256, 0, stream>>>(
        x, wk, wq, wv, bk, bq, bv, nullptr, kbuf, qbuf, vbuf);

    scores_mfma<<<B_ * C_, 256, 0, stream>>>(kbuf, qbuf);        // qbuf := ST
    softmax_pack<<<4096, 256, 0, stream>>>(qbuf, attnH, attnL);  // kbuf := attn^T tiles
    av_mfma<<<B_ * C_, 256, 0, stream>>>(vbuf, attnH, attnL);    // vbuf := out2

    // wo conv + bias + residual, panel structure
    conv_panel<1, true><<<gP, 256, 0, stream>>>(
        vbuf, wo, nullptr, nullptr, bo, nullptr, nullptr, x, out, nullptr, nullptr);
}